// Round 6
// baseline (534.670 us; speedup 1.0000x reference)
//
#include <hip/hip_runtime.h>

#define BATCHES 32
#define NAG 6          // agents (N)
#define KSZ 256        // KS
#define QSZ 256        // QS
#define CHW 524288     // 512*32*32 floats per (b,n) slice
#define CHW4 131072    // CHW/4 float4s  (== 1<<17)
#define WS_ITER 4      // quads per thread in wsum
#define WS_BLKX 128    // CHW4 / (256 * WS_ITER)

typedef float f32x4 __attribute__((ext_vector_type(4)));  // native clang vector
                                                          // (nontemporal builtins
                                                          // reject HIP_vector_type)

// ---------------------------------------------------------------------------
// Kernel 1: query = q @ W^T + b ; scores = k . query ; sparsemax over N=6.
// One block per batch. 256 threads: each thread computes one query element.
// Wave 0 then computes the 6 scores (coalesced k loads + shuffle reduce) and
// lane 0 runs sparsemax exactly as the reference (f32 throughout).
// ---------------------------------------------------------------------------
__global__ __launch_bounds__(256) void attn_kernel(
    const float* __restrict__ q,     // [B,1,QSZ]
    const float* __restrict__ kmat,  // [B,NAG,KSZ]
    const float* __restrict__ W,     // [KSZ,QSZ] row-major (row = output k idx)
    const float* __restrict__ bias,  // [KSZ]
    float* __restrict__ wts,         // ws: [B,8] sparsemax weights (padded)
    float* __restrict__ attn_out)    // d_out tail: [B,1,NAG]
{
    __shared__ __align__(16) float q_lds[QSZ];
    __shared__ __align__(16) float query_lds[KSZ];

    const int b = blockIdx.x;
    const int t = threadIdx.x;

    q_lds[t] = q[b * QSZ + t];
    __syncthreads();

    // query[t] = dot(q[b,:], W[t,:]) + bias[t]
    {
        const f32x4* W4 = reinterpret_cast<const f32x4*>(W + t * QSZ);
        const f32x4* q4 = reinterpret_cast<const f32x4*>(q_lds);
        float acc = 0.0f;
        #pragma unroll 8
        for (int d = 0; d < QSZ / 4; ++d) {
            f32x4 wv = W4[d];
            f32x4 qv = q4[d];
            acc += wv.x * qv.x + wv.y * qv.y + wv.z * qv.z + wv.w * qv.w;
        }
        query_lds[t] = acc + bias[t];
    }
    __syncthreads();

    // Wave 0: six dot products k[b,n,:] . query[:], then sparsemax on lane 0.
    if (t < 64) {
        float part[NAG];
        #pragma unroll
        for (int n = 0; n < NAG; ++n) part[n] = 0.0f;

        const float* kb = kmat + (size_t)b * NAG * KSZ;
        #pragma unroll
        for (int j = 0; j < 4; ++j) {
            const int kk = t + j * 64;            // coalesced across lanes
            const float qv = query_lds[kk];
            #pragma unroll
            for (int n = 0; n < NAG; ++n)
                part[n] += kb[n * KSZ + kk] * qv;
        }
        // 64-lane shuffle reduction for each of the 6 scores
        #pragma unroll
        for (int n = 0; n < NAG; ++n) {
            #pragma unroll
            for (int off = 32; off > 0; off >>= 1)
                part[n] += __shfl_down(part[n], off);
        }

        if (t == 0) {
            // sparsemax over the 6 scores (exact reference recipe, f32)
            float z[NAG], zs[NAG];
            #pragma unroll
            for (int n = 0; n < NAG; ++n) { z[n] = part[n]; zs[n] = part[n]; }
            // insertion sort, descending
            for (int i = 1; i < NAG; ++i) {
                float key = zs[i];
                int j = i - 1;
                while (j >= 0 && zs[j] < key) { zs[j + 1] = zs[j]; --j; }
                zs[j + 1] = key;
            }
            float cums[NAG];
            float run = 0.0f;
            #pragma unroll
            for (int j = 0; j < NAG; ++j) { run += zs[j]; cums[j] = run; }
            int kcnt = 0;
            #pragma unroll
            for (int j = 0; j < NAG; ++j)
                if (1.0f + (float)(j + 1) * zs[j] > cums[j]) kcnt++;
            const float tau = (cums[kcnt - 1] - 1.0f) / (float)kcnt;

            #pragma unroll
            for (int n = 0; n < NAG; ++n) {
                const float p = fmaxf(z[n] - tau, 0.0f);
                wts[b * 8 + n] = p;                  // for kernel 2
                attn_out[b * NAG + n] = p;           // output #2 [B,1,N]
            }
        }
    }
}

// ---------------------------------------------------------------------------
// Kernel 2: out[b,chw] = sum_n wts[b,n] * v[b,n,chw]   (memory-bound, 16B/lane)
// grid = (WS_BLKX, BATCHES); each thread does WS_ITER quads within ONE batch,
// so the 6 weights load once into registers. Nontemporal: v/out are touched
// exactly once (streaming), keep them out of L2/L3.
// ---------------------------------------------------------------------------
__global__ __launch_bounds__(256) void wsum_kernel(
    const f32x4* __restrict__ v4,    // [B,NAG,CHW4]
    const float* __restrict__ wts,   // [B,8]
    f32x4* __restrict__ out4)        // [B,CHW4]
{
    const int b = blockIdx.y;
    float w[NAG];
    #pragma unroll
    for (int n = 0; n < NAG; ++n) w[n] = wts[b * 8 + n];

    const f32x4* vb = v4 + (size_t)b * NAG * CHW4;
    f32x4* ob = out4 + (size_t)b * CHW4;

    int off = blockIdx.x * 256 + threadIdx.x;     // stride WS_BLKX*256 per iter
    #pragma unroll
    for (int it = 0; it < WS_ITER; ++it, off += WS_BLKX * 256) {
        f32x4 a = w[0] * __builtin_nontemporal_load(vb + off);
        #pragma unroll
        for (int n = 1; n < NAG; ++n) {
            a += w[n] * __builtin_nontemporal_load(vb + (size_t)n * CHW4 + off);
        }
        __builtin_nontemporal_store(a, ob + off);
    }
}

extern "C" void kernel_launch(void* const* d_in, const int* in_sizes, int n_in,
                              void* d_out, int out_size, void* d_ws, size_t ws_size,
                              hipStream_t stream) {
    const float* q    = (const float*)d_in[0];   // [32,1,256]
    const float* kmat = (const float*)d_in[1];   // [32,6,256]
    const float* v    = (const float*)d_in[2];   // [32,6,512,32,32]
    const float* W    = (const float*)d_in[3];   // [256,256]
    const float* bias = (const float*)d_in[4];   // [256]

    float* out      = (float*)d_out;                       // [32,512,32,32]
    float* attn_out = out + (size_t)BATCHES * CHW;         // [32,1,6] tail
    float* wts      = (float*)d_ws;                        // [32,8] scratch

    attn_kernel<<<BATCHES, 256, 0, stream>>>(q, kmat, W, bias, wts, attn_out);
    wsum_kernel<<<dim3(WS_BLKX, BATCHES), 256, 0, stream>>>(
        (const f32x4*)v, wts, (f32x4*)out);
}